// Round 10
// baseline (205.096 us; speedup 1.0000x reference)
//
#include <hip/hip_runtime.h>
#include <stdint.h>

// AM-softmax loss, fused on MI355X (gfx950) — round 18.
//
// vs round 17 (198.5 us; gemm 82.0, MfmaUtil 41.5, Occ 37%, VGPR 64):
//  * r17 proved occupancy wasn't the gemm lever (+4 blocks/CU -> +2%).
//    gemm is pinned ~82 us by the 2-barrier band structure (m97-style
//    ~40% MfmaUtil ceiling); breaking that needs a counted-vmcnt schedule
//    port — deferred. Budget: 80 fixed + gemm 82 + prep ~33 + fin ~3.
//  * This round: prep_all W-branch only. Old pattern: lane (m,q) loads
//    W[(t16*16+m)*D + q*8] -> each instr touches 16 rows (768 B stride) =
//    16 segments/instr (~2x transactions; prep ran 1.8x its 18.7 us
//    traffic floor). New: block-cooperative stage of 4 tiles (64 rows,
//    48 KB contiguous) via linear f=i*256+tid float4 indexing -> every
//    load instr is 1 KB contiguous (8 segments, minimal). LDS [64][196]
//    (+4-word row pad -> fragment reads 2-way bank-aliased = free),
//    one barrier, then per-wave fragment read + cvtpk + short8 store as
//    before. row>=C zero-guard replaces the real/phantom branch (C is an
//    exact 16-row boundary).
//  * gemm_lse / finalize_tiny / x-branch byte-identical to r17.

constexpr int N  = 2048;
constexpr int D  = 192;               // K
constexpr int C  = 100000;
constexpr int KT = D / 32;            // 6 k-tiles of 32
constexpr int TILE = 512;             // elems per 16x32 fragment tile
constexpr int RT16 = C / 16;          // 6250 real 16-col tiles
constexpr int TPG = 12;               // 16-col tiles per block (4 waves x 3)
constexpr int CX = 523;               // col groups: 523*12 = 6276 tiles
constexpr int NT16 = CX * TPG;        // 6276 tiles = 100416 cols
constexpr float PHANTOM = (float)(NT16 * 16 - C);   // 416 exact ones
constexpr int BANDS = 8;              // 32-row bands per block (256 rows)
constexpr int RYB = N / (32 * BANDS); // 8 row groups
constexpr int BUF = 2 * KT * TILE;    // 6144 ushort = 12 KB per band buffer
constexpr int NXB = N / 4;            // 512 prep_x blocks
constexpr int CXP = 528;              // cx padded to multiple of 8 (XCD remap)

#define S_SCALE 30.0f
#define MARGIN  0.2f
#define S_LOG2E 43.2808512266689f     // 30 * log2(e)

using short8 = __attribute__((ext_vector_type(8))) short;   // 8 bf16 (4 VGPRs)
using f32x4  = __attribute__((ext_vector_type(4))) float;   // MFMA C/D

typedef __attribute__((address_space(1))) const void GV;
typedef __attribute__((address_space(3))) void LV;

__device__ inline unsigned short f2bf(float f) {  // fp32 -> bf16 RNE
  unsigned int u = __float_as_uint(f);
  u += 0x7fffu + ((u >> 16) & 1u);
  return (unsigned short)(u >> 16);
}

__device__ inline unsigned int cvtpk(float lo, float hi) {  // RNE pack, = f2bf
  unsigned int r;
  asm("v_cvt_pk_bf16_f32 %0, %1, %2" : "=v"(r) : "v"(lo), "v"(hi));
  return r;
}

// packed fragment index (ushort units) for element (row r, k):
// tile (r>>4, k>>5), lane = (r&15) + ((k>>3)&3)*16, elem k&7.
__device__ inline int pack_idx(int r, int k) {
  return ((r >> 4) * KT + (k >> 5)) * TILE + (((k >> 3) & 3) * 16 + (r & 15)) * 8 + (k & 7);
}

// Sum across each 16-lane DPP row; result valid in all 16 lanes.
__device__ inline float row_sum16(float v) {
  int x;
  x = __float_as_int(v);
  v += __int_as_float(__builtin_amdgcn_update_dpp(0, x, 0x128, 0xF, 0xF, true)); // row_ror:8
  x = __float_as_int(v);
  v += __int_as_float(__builtin_amdgcn_update_dpp(0, x, 0x124, 0xF, 0xF, true)); // row_ror:4
  x = __float_as_int(v);
  v += __int_as_float(__builtin_amdgcn_update_dpp(0, x, 0x04E, 0xF, 0xF, true)); // quad_perm xor2
  x = __float_as_int(v);
  v += __int_as_float(__builtin_amdgcn_update_dpp(0, x, 0x0B1, 0xF, 0xF, true)); // quad_perm xor1
  return v;
}

// ---------------- fused prep: x-normalize+pack + target logit + W pack ----
// W-blocks: 4 tiles (64 W rows) staged cooperatively through LDS with
// fully-coalesced global loads, then per-wave fragment reads (2-way bank
// aliased via +4-word row pad) + cvtpk + coalesced short8 stores.
__global__ __launch_bounds__(256) void prep_all(
    const float* __restrict__ x, const float* __restrict__ W,
    const int* __restrict__ label,
    unsigned short* __restrict__ xnb, unsigned short* __restrict__ Wb,
    float* __restrict__ aux, float* __restrict__ rowsum,
    float* __restrict__ out) {
  __shared__ alignas(16) float stg[64 * 196];   // 50.2 KB (W-blocks only)
  const int bid  = blockIdx.x;
  const int tid  = threadIdx.x;
  const int lane = tid & 63, wave = tid >> 6;
  if (bid == 0 && tid == 0) out[0] = 0.0f;   // for finalize atomic

  if (bid < NXB) {
    // ---- one wave per x row: normalize + pack + target logit ----
    const int row = bid * 4 + wave;
    const float* xr = x + (size_t)row * D;
    float v0 = xr[lane], v1 = xr[lane + 64], v2 = xr[lane + 128];
    float ss = v0 * v0 + v1 * v1 + v2 * v2;
    const int lab = label[row];
    const float* wr = W + (size_t)lab * D;
    float d = v0 * wr[lane] + v1 * wr[lane + 64] + v2 * wr[lane + 128];
#pragma unroll
    for (int off = 32; off > 0; off >>= 1) {
      ss += __shfl_xor(ss, off, 64);
      d  += __shfl_xor(d,  off, 64);
    }
    const float rinv = rsqrtf(ss);
    const float inv = rinv * S_LOG2E;
    xnb[pack_idx(row, lane)]       = f2bf(v0 * inv);
    xnb[pack_idx(row, lane + 64)]  = f2bf(v1 * inv);
    xnb[pack_idx(row, lane + 128)] = f2bf(v2 * inv);
    if (lane == 0) {
      aux[row]    = d * rinv;   // target logit (unscaled)
      rowsum[row] = 0.0f;       // accumulator for gemm atomics
    }
  } else {
    const int t16base = (bid - NXB) * 4;     // 4 consecutive 16-col tiles
    // ---- cooperative coalesced stage: 64 rows x 48 float4 = 48 KB ----
#pragma unroll
    for (int i = 0; i < 12; ++i) {
      const int f = i * 256 + tid;           // linear float4 index (0..3071)
      const int row = f / 48, c4 = f - row * 48;
      const int grow = t16base * 16 + row;
      float4 v = make_float4(0.0f, 0.0f, 0.0f, 0.0f);
      if (grow < C) v = *(const float4*)(W + (size_t)grow * D + c4 * 4);
      *(float4*)&stg[row * 196 + c4 * 4] = v;   // row pad +4 words
    }
    __syncthreads();
    // ---- per-wave fragment read + cvtpk + coalesced store ----
    const int m = lane & 15, q = lane >> 4;
    const int t16 = t16base + wave;
    const float* rsrc = &stg[(wave * 16 + m) * 196 + q * 8];
    unsigned short* dst = Wb + (size_t)t16 * KT * TILE + lane * 8;
#pragma unroll
    for (int ks = 0; ks < KT; ++ks) {
      const float4 f0 = *(const float4*)(rsrc + ks * 32);
      const float4 f1 = *(const float4*)(rsrc + ks * 32 + 4);
      union { uint4 u; short8 s; } cv;
      cv.u.x = cvtpk(f0.x, f0.y);
      cv.u.y = cvtpk(f0.z, f0.w);
      cv.u.z = cvtpk(f1.x, f1.y);
      cv.u.w = cvtpk(f1.z, f1.w);
      *(short8*)(dst + (size_t)ks * TILE) = cv.s;
    }
  }
}

// issue one 12 KB band DMA into buffer (BN&1): 768 x 16 B over 256 threads
#define PREFETCH(BN)                                                          \
  {                                                                           \
    const unsigned short* slab = xnb + (size_t)(ry * BANDS + (BN)) * BUF;     \
    char* dst = (char*)&As[((BN) & 1) * BUF];                                 \
    _Pragma("unroll")                                                         \
    for (int i = 0; i < 3; ++i) {                                             \
      const int chunk = tid + i * 256;                                        \
      __builtin_amdgcn_global_load_lds(                                       \
          (GV*)((const char*)slab + (size_t)chunk * 16),                      \
          (LV*)(dst + (size_t)chunk * 16), 16, 0, 0);                         \
    }                                                                         \
  }

// ---------------- main fused GEMM + exp-rowsum ----------------------------
// Grid CXP*RYB (4224). XCD-aware map (proven): xcd=bid&7, j=bid>>3, ry=j&7,
// cx=(j>>3)*8+xcd -> 8 ry-blocks of one cx share one XCD's L2 (Wb panel
// fetched once). Block = 4 waves; wave owns 48 cols (breg from packed Wb).
// 8 bands of 32 rows, A double-buffered (12 KB each), DMA prefetch one band
// ahead. LDS 28 KB + 64 VGPR -> 4 blocks/CU. Per-row exp-sums atomicAdd
// into rowsum[N].
__global__ __launch_bounds__(256, 4) void gemm_lse(
    const unsigned short* __restrict__ xnb,  // packed [128 row-tiles][KT][512]
    const unsigned short* __restrict__ Wb,   // packed [NT16][KT][512]
    float* __restrict__ rowsum) {            // [N] atomic accumulator
  __shared__ alignas(16) unsigned short As[2 * BUF];   // 24 KB (double buffer)
  __shared__ alignas(16) float rs_lds[4][256];         // 4 KB

  const int tid = threadIdx.x;
  const int bid = blockIdx.x;
  const int xcd = bid & 7, j = bid >> 3;
  const int ry = j & 7;
  const int cx = (j >> 3) * 8 + xcd;
  if (cx >= CX) return;                     // 40 phantom blocks (pad to 528)

  // ---- issue DMA for band 0 into buf 0 (12 KB, contiguous packed) ----
  {
    const unsigned short* slab = xnb + (size_t)(ry * BANDS) * BUF;
#pragma unroll
    for (int i = 0; i < 3; ++i) {            // 768 x 16 B
      const int chunk = tid + i * 256;
      __builtin_amdgcn_global_load_lds(
          (GV*)((const char*)slab + (size_t)chunk * 16),
          (LV*)((char*)As + (size_t)chunk * 16), 16, 0, 0);
    }
  }

  const int lane = tid & 63, wave = tid >> 6;
  const int m = lane & 15, quad = lane >> 4;

  // ---- B fragments from packed Wb (18 coalesced 1 KB wave-loads) ----
  short8 breg[3][KT];
#pragma unroll
  for (int tc = 0; tc < 3; ++tc)
#pragma unroll
    for (int ks = 0; ks < KT; ++ks)
      breg[tc][ks] = *(const short8*)(
          Wb + (size_t)((cx * TPG + wave * 3 + tc) * KT + ks) * TILE + lane * 8);

  const f32x4 zero4 = {0.0f, 0.0f, 0.0f, 0.0f};

#pragma unroll
  for (int b = 0; b < BANDS; ++b) {        // fully unrolled: b compile-time
    __syncthreads();   // drains vmcnt: band b's DMA (issued one band ago)

    if (b + 1 < BANDS) PREFETCH(b + 1);

    const unsigned short* Ab = &As[(b & 1) * BUF];

    f32x4 acc[2][3];
#pragma unroll
    for (int t2 = 0; t2 < 2; ++t2)
#pragma unroll
      for (int c = 0; c < 3; ++c) acc[t2][c] = zero4;

#pragma unroll
    for (int ks = 0; ks < KT; ++ks) {
      const short8 af0 = *(const short8*)(&Ab[(0 * KT + ks) * TILE + lane * 8]);
      const short8 af1 = *(const short8*)(&Ab[(1 * KT + ks) * TILE + lane * 8]);
#pragma unroll
      for (int c = 0; c < 3; ++c)
        acc[0][c] = __builtin_amdgcn_mfma_f32_16x16x32_bf16(
            af0, breg[c][ks], acc[0][c], 0, 0, 0);
#pragma unroll
      for (int c = 0; c < 3; ++c)
        acc[1][c] = __builtin_amdgcn_mfma_f32_16x16x32_bf16(
            af1, breg[c][ks], acc[1][c], 0, 0, 0);
    }

    // ---- epilogue: exp2 (arg pre-scaled; phantom cols give exactly 1) ----
#pragma unroll
    for (int t2 = 0; t2 < 2; ++t2) {
      float rv0 = 0.f, rv1 = 0.f, rv2 = 0.f, rv3 = 0.f;
#pragma unroll
      for (int c = 0; c < 3; ++c) {
        rv0 += __builtin_amdgcn_exp2f(acc[t2][c][0]);
        rv1 += __builtin_amdgcn_exp2f(acc[t2][c][1]);
        rv2 += __builtin_amdgcn_exp2f(acc[t2][c][2]);
        rv3 += __builtin_amdgcn_exp2f(acc[t2][c][3]);
      }
      rv0 = row_sum16(rv0);
      rv1 = row_sum16(rv1);
      rv2 = row_sum16(rv2);
      rv3 = row_sum16(rv3);
      if (m == 0)
        *(float4*)(&rs_lds[wave][b * 32 + t2 * 16 + quad * 4]) =
            make_float4(rv0, rv1, rv2, rv3);
    }
  }

  __syncthreads();  // all waves' rowsums in LDS
  const float s = rs_lds[0][tid] + rs_lds[1][tid] + rs_lds[2][tid] + rs_lds[3][tid];
  atomicAdd(&rowsum[ry * 256 + tid], s);    // 523 adds/address, spread in time
}

// ---------------- finalize: per-row loss + in-kernel mean reduce ----------
// 8 blocks x 256 threads, one thread per row. Reads are fully coalesced.
__global__ __launch_bounds__(256) void finalize_tiny(
    const float* __restrict__ aux, const float* __restrict__ rowsum,
    float* __restrict__ out) {
  const int row  = blockIdx.x * 256 + threadIdx.x;
  const int lane = threadIdx.x & 63, wave = threadIdx.x >> 6;
  const float tgt   = aux[row];
  const float numer = S_SCALE * (tgt - MARGIN);
  // remove phantom-ones, swap label column's exp for margin-adjusted exp
  const float se = rowsum[row] - PHANTOM - __expf(S_SCALE * tgt) + __expf(numer);
  float L = numer - logf(se);
#pragma unroll
  for (int off = 32; off > 0; off >>= 1) L += __shfl_xor(L, off, 64);
  __shared__ float part[4];
  if (lane == 0) part[wave] = L;
  __syncthreads();
  if (threadIdx.x == 0) {
    const float blocksum = part[0] + part[1] + part[2] + part[3];
    atomicAdd(out, -blocksum * (1.0f / (float)N));
  }
}

// ---------------- host ----------------------------------------------------
extern "C" void kernel_launch(void* const* d_in, const int* in_sizes, int n_in,
                              void* d_out, int out_size, void* d_ws, size_t ws_size,
                              hipStream_t stream) {
  const float* x     = (const float*)d_in[0];
  const float* W     = (const float*)d_in[1];
  const int*   label = (const int*)d_in[2];
  float*       out   = (float*)d_out;

  char* ws = (char*)d_ws;
  size_t off = 0;
  unsigned short* xnb = (unsigned short*)(ws + off); off += (size_t)N * D * 2;            // 768 KB
  unsigned short* Wb  = (unsigned short*)(ws + off); off += (size_t)NT16 * KT * TILE * 2; // 38.6 MB
  float* aux    = (float*)(ws + off); off += (size_t)N * 4;                                // 8 KB
  float* rowsum = (float*)(ws + off); off += (size_t)N * 4;                                // 8 KB

  prep_all<<<NXB + NT16 / 4, 256, 0, stream>>>(x, W, label, xnb, Wb, aux, rowsum, out);

  gemm_lse<<<CXP * RYB, 256, 0, stream>>>(xnb, Wb, rowsum);

  finalize_tiny<<<N / 256, 256, 0, stream>>>(aux, rowsum, out);
}